// Round 10
// baseline (88.165 us; speedup 1.0000x reference)
//
#include <hip/hip_runtime.h>
#include <math.h>

#define C_IN 2048
#define N_EXP 64
#define TPB 32            // tokens per block
#define NSC 16            // superchunks of 128 cols
#define DELTA  3e-4f      // risky-gap threshold
#define DELTA2 1e-3f      // candidate window around v2

typedef __bf16 bf16x8 __attribute__((ext_vector_type(8)));
typedef float f32x4 __attribute__((ext_vector_type(4)));

__device__ __forceinline__ void cvt_split(float f, ushort& h, ushort& l) {
    uint u = __float_as_uint(f);
    uint hr = (u + (0x7FFFu + ((u >> 16) & 1u))) >> 16;
    h = (ushort)hr;
    float hf = __uint_as_float(hr << 16);
    uint v = __float_as_uint(f - hf);
    l = (ushort)((v + (0x7FFFu + ((v >> 16) & 1u))) >> 16);
}

// W [64][2048] fp32 -> frag-major bf16 hi/lo per (wave-group wg, kstep ks):
// o = (wg*64+ks)*512 + l*8 + j  <->  e = wg*16+(l&15), k = ks*32+(l>>4)*8+j.
// One (wg,ks) block = 1 KB contiguous -> staged by ONE gload_lds instr.
__global__ void conv_w_kernel(const float* __restrict__ W,
                              ushort* __restrict__ whf, ushort* __restrict__ wlf) {
    const int o = blockIdx.x * 256 + threadIdx.x;   // 0..131071
    const int wg = o >> 15;
    const int ks = (o >> 9) & 63;
    const int l = (o >> 3) & 63;
    const int j = o & 7;
    const int e = wg * 16 + (l & 15);
    const int k = ks * 32 + (l >> 4) * 8 + j;
    ushort h, lo;
    cvt_split(W[e * C_IN + k], h, lo);
    whf[o] = h;
    wlf[o] = lo;
}

__device__ __forceinline__ void glds16(const void* g, void* l) {
    __builtin_amdgcn_global_load_lds(
        (const __attribute__((address_space(1))) uint32_t*)g,
        (__attribute__((address_space(3))) uint32_t*)l, 16, 0, 0);
}

__device__ __forceinline__ void cvt8(const float4 a, const float4 b2,
                                     uint4& hv, uint4& lv) {
    ushort h[8], q[8];
    cvt_split(a.x, h[0], q[0]);  cvt_split(a.y, h[1], q[1]);
    cvt_split(a.z, h[2], q[2]);  cvt_split(a.w, h[3], q[3]);
    cvt_split(b2.x, h[4], q[4]); cvt_split(b2.y, h[5], q[5]);
    cvt_split(b2.z, h[6], q[6]); cvt_split(b2.w, h[7], q[7]);
    hv = (uint4){(uint)h[0] | ((uint)h[1] << 16), (uint)h[2] | ((uint)h[3] << 16),
                 (uint)h[4] | ((uint)h[5] << 16), (uint)h[6] | ((uint)h[7] << 16)};
    lv = (uint4){(uint)q[0] | ((uint)q[1] << 16), (uint)q[2] | ((uint)q[3] << 16),
                 (uint)q[4] | ((uint)q[5] << 16), (uint)q[6] | ((uint)q[7] << 16)};
}

#define VMW(N) do { asm volatile("s_waitcnt vmcnt(" #N ")" ::: "memory");     \
                    __builtin_amdgcn_sched_barrier(0); } while (0)

// stage x superchunk SCN into buffer BB: 4 instrs/wave, each fills 2 LDS rows
// (1 KB linear dest) from two contiguous 512-B global bursts (pre-swizzled
// 16-B units so compute reads are bank-spread).
#define STAGEX(BB, SCN) do {                                                  \
    char* xd_ = smem + (BB) * 16384;                                          \
    _Pragma("unroll") for (int i_ = 0; i_ < 4; ++i_) {                        \
        const int row0_ = w * 8 + 2 * i_;                                     \
        const int r_ = row0_ + (l >> 5);                                      \
        const int su_ = (l & 31) ^ ((r_ & 7) << 1);                           \
        glds16((const float*)x + (size_t)(t0 + r_) * C_IN + (SCN) * 128 + su_ * 4, \
               (float*)(xd_ + row0_ * 512));                                  \
    }                                                                         \
    __builtin_amdgcn_sched_barrier(0);                                        \
} while (0)

// One kstep: optionally stage W(ksg+2) (wave-private slot (K+2)&3), counted
// wait for this kstep's W+x, ds_read A(fp32)+B(bf16), cvt, 6 MFMA.
#define KSTEP(K, VMN, DOSTG) do {                                             \
    if (DOSTG) {                                                              \
        const int ksg2_ = sc4 + (K) + 2;                                      \
        const size_t wo_ = ((size_t)(w * 64 + ksg2_)) * 512 + l * 8;          \
        glds16(whf + wo_, wsl + (((K) + 2) & 3) * 2048);                      \
        glds16(wlf + wo_, wsl + (((K) + 2) & 3) * 2048 + 1024);               \
        __builtin_amdgcn_sched_barrier(0);                                    \
    }                                                                         \
    VMW(VMN);                                                                 \
    {                                                                         \
        const int uo_ = (((K) * 8 + kg2) ^ sw) * 16;                         \
        float4 a0lo_ = *(const float4*)(xb + aoff0 + uo_);                    \
        float4 a0hi_ = *(const float4*)(xb + aoff0 + uo_ + 16);               \
        float4 a1lo_ = *(const float4*)(xb + aoff1 + uo_);                    \
        float4 a1hi_ = *(const float4*)(xb + aoff1 + uo_ + 16);               \
        uint4 bhu_ = *(const uint4*)(wsl + ((K) & 3) * 2048 + l * 16);        \
        uint4 blu_ = *(const uint4*)(wsl + ((K) & 3) * 2048 + 1024 + l * 16); \
        uint4 h0_, l0_, h1_, l1_;                                             \
        cvt8(a0lo_, a0hi_, h0_, l0_);                                         \
        cvt8(a1lo_, a1hi_, h1_, l1_);                                         \
        bf16x8 ah0_ = __builtin_bit_cast(bf16x8, h0_);                        \
        bf16x8 al0_ = __builtin_bit_cast(bf16x8, l0_);                        \
        bf16x8 ah1_ = __builtin_bit_cast(bf16x8, h1_);                        \
        bf16x8 al1_ = __builtin_bit_cast(bf16x8, l1_);                        \
        bf16x8 bh_ = __builtin_bit_cast(bf16x8, bhu_);                        \
        bf16x8 bl_ = __builtin_bit_cast(bf16x8, blu_);                        \
        __builtin_amdgcn_s_setprio(1);                                        \
        acc0 = __builtin_amdgcn_mfma_f32_16x16x32_bf16(ah0_, bh_, acc0, 0, 0, 0); \
        acc1 = __builtin_amdgcn_mfma_f32_16x16x32_bf16(ah1_, bh_, acc1, 0, 0, 0); \
        acc0 = __builtin_amdgcn_mfma_f32_16x16x32_bf16(al0_, bh_, acc0, 0, 0, 0); \
        acc1 = __builtin_amdgcn_mfma_f32_16x16x32_bf16(al1_, bh_, acc1, 0, 0, 0); \
        acc0 = __builtin_amdgcn_mfma_f32_16x16x32_bf16(ah0_, bl_, acc0, 0, 0, 0); \
        acc1 = __builtin_amdgcn_mfma_f32_16x16x32_bf16(ah1_, bl_, acc1, 0, 0, 0); \
        __builtin_amdgcn_s_setprio(0);                                        \
    }                                                                         \
} while (0)

// Main: 512 blocks x 256 thr (4 waves), 64 KB LDS -> 2 blocks/CU.
// Wave w: 32 tokens x experts [w*16,w*16+16) x FULL K. ALL hot-loop global
// traffic via global_load_lds (no compiler vmem => exact hand-counted vmcnt).
// x: fp32 tile [32][128] dbuf, staged 1 superchunk ahead, 512-B bursts/row.
// W: frag-major bf16 hi/lo, wave-private 4-slot ring, staged 2 ksteps ahead,
// 1-KB contiguous bursts. One raw s_barrier per 4 ksteps; vmcnt never 0
// mid-loop (8/8/4/4; tail 4/4/2/0). Epilogue: partials pitch-65 + verified
// softmax/top-2/fp32-repair.
__global__ __launch_bounds__(256, 2) void topk_gate_kernel(
    const float* __restrict__ x, const float* __restrict__ Wf,
    const float* __restrict__ b, const ushort* __restrict__ whf,
    const ushort* __restrict__ wlf, float* __restrict__ out)
{
    // bytes [0,32768): x dbuf (2 x [32 rows][512 B] fp32)
    // bytes [32768,65536): W rings, wave w at 32768+w*8192, 4 slots x 2 KB
    __shared__ __align__(16) char smem[65536];

    const int tid = threadIdx.x;
    const int w = tid >> 6, l = tid & 63;
    const int tr = l & 15, kg = l >> 4;
    const int kg2 = kg * 2;
    const int sw = (tr & 7) << 1;
    const int aoff0 = tr * 512;
    const int aoff1 = (tr + 16) * 512;
    const int t0 = blockIdx.x * TPB;
    char* wsl = smem + 32768 + w * 8192;

    f32x4 acc0 = {0.f, 0.f, 0.f, 0.f};
    f32x4 acc1 = {0.f, 0.f, 0.f, 0.f};

    // ---- prologue: x(0) + W(0),W(1); wait x; barrier ----
    STAGEX(0, 0);
    {
        const size_t wo0 = ((size_t)(w * 64 + 0)) * 512 + l * 8;
        glds16(whf + wo0, wsl + 0 * 2048);
        glds16(wlf + wo0, wsl + 0 * 2048 + 1024);
        const size_t wo1 = ((size_t)(w * 64 + 1)) * 512 + l * 8;
        glds16(whf + wo1, wsl + 1 * 2048);
        glds16(wlf + wo1, wsl + 1 * 2048 + 1024);
        __builtin_amdgcn_sched_barrier(0);
    }
    VMW(4);
    __builtin_amdgcn_s_barrier();

    int sc4 = 0;
#pragma unroll 1
    for (int sc = 0; sc < NSC - 1; ++sc) {
        const char* xb = smem + (sc & 1) * 16384;
        STAGEX((sc + 1) & 1, sc + 1);
        KSTEP(0, 8, 1);
        KSTEP(1, 8, 1);
        KSTEP(2, 4, 1);
        KSTEP(3, 4, 1);
        VMW(8);                       // x(sc+1) landed; 8 W stay in flight
        __builtin_amdgcn_s_barrier();
        sc4 += 4;
    }
    {   // tail superchunk 15 (no x staging; W 62,63 staged at k0,k1)
        const char* xb = smem + 16384;
        KSTEP(0, 4, 1);
        KSTEP(1, 4, 1);
        KSTEP(2, 2, 0);
        KSTEP(3, 0, 0);
    }

    // ---- partials (overlay xbuf0; pitch 65), one sync, softmax/top-2 ----
    float* part = (float*)smem;   // [32][65] fp32
#pragma unroll
    for (int r = 0; r < 4; ++r) {
        part[(kg * 4 + r) * 65 + w * 16 + tr] = acc0[r];
        part[(16 + kg * 4 + r) * 65 + w * 16 + tr] = acc1[r];
    }
    __syncthreads();

    const int e = l;
    const float be = b[e];
    for (int ti = 0; ti < 8; ++ti) {
        const int t = w * 8 + ti;
        float logit = part[t * 65 + e] + be;

        float v1, v2, v3; int i1, i2;
        for (int pass = 0; pass < 2; ++pass) {
            v1 = logit; i1 = e;
#pragma unroll
            for (int off = 32; off >= 1; off >>= 1) {
                float ov = __shfl_xor(v1, off, 64);
                int   oi = __shfl_xor(i1, off, 64);
                if (ov > v1 || (ov == v1 && oi < i1)) { v1 = ov; i1 = oi; }
            }
            v2 = (e == i1) ? -3.4e38f : logit;
            i2 = (e == i1) ? N_EXP : e;
#pragma unroll
            for (int off = 32; off >= 1; off >>= 1) {
                float ov = __shfl_xor(v2, off, 64);
                int   oi = __shfl_xor(i2, off, 64);
                if (ov > v2 || (ov == v2 && oi < i2)) { v2 = ov; i2 = oi; }
            }
            v3 = (e == i1 || e == i2) ? -3.4e38f : logit;
#pragma unroll
            for (int off = 32; off >= 1; off >>= 1) {
                float ov = __shfl_xor(v3, off, 64);
                v3 = (ov > v3) ? ov : v3;
            }
            if (pass == 1) break;
            const bool risky = (v1 - v2 < DELTA) || (v2 - v3 < DELTA);
            if (!risky) break;
            unsigned long long cm = __ballot(logit >= v2 - DELTA2);
            const float* xr = x + (size_t)(t0 + t) * C_IN;
            while (cm) {
                const int ce = __ffsll((unsigned long long)cm) - 1;
                cm &= cm - 1;
                const float* wr = Wf + (size_t)ce * C_IN;
                float p = 0.f;
#pragma unroll 8
                for (int i = 0; i < 32; ++i)
                    p = fmaf(xr[l + 64 * i], wr[l + 64 * i], p);
#pragma unroll
                for (int off = 32; off >= 1; off >>= 1)
                    p += __shfl_xor(p, off, 64);
                if (e == ce) logit = p + be;
            }
        }

        float ex = expf(logit - v1);
        float ssum = ex;
#pragma unroll
        for (int off = 32; off >= 1; off >>= 1)
            ssum += __shfl_xor(ssum, off, 64);
        const float inv = 1.0f / ssum;
        const float p1 = inv;
        const float p2 = expf(v2 - v1) * inv;
        const float o = (e == i1) ? p1 : ((e == i2) ? p2 : 0.0f);
        out[(size_t)(t0 + t) * N_EXP + e] = o;
    }
}

extern "C" void kernel_launch(void* const* d_in, const int* in_sizes, int n_in,
                              void* d_out, int out_size, void* d_ws, size_t ws_size,
                              hipStream_t stream) {
    const float* x = (const float*)d_in[0];   // [4,4096,2048]
    const float* W = (const float*)d_in[1];   // [64,2048]
    const float* b = (const float*)d_in[2];   // [64]
    float* out = (float*)d_out;               // [4,4096,64]

    ushort* whf = (ushort*)d_ws;              // frag-major bf16 hi, 256 KB
    ushort* wlf = whf + N_EXP * C_IN;         // frag-major bf16 lo, 256 KB

    conv_w_kernel<<<512, 256, 0, stream>>>(W, whf, wlf);

    const int tokens = in_sizes[0] / C_IN;    // 16384
    const int grid = tokens / TPB;            // 512
    topk_gate_kernel<<<grid, 256, 0, stream>>>(x, W, b, whf, wlf, out);
}

// Round 12
// 83.783 us; speedup vs baseline: 1.0523x; 1.0523x over previous
//
#include <hip/hip_runtime.h>
#include <math.h>

#define C_IN 2048
#define N_EXP 64
#define TPB 64            // tokens per block
#define NSLICE 16         // K slices of 128 cols (4 ksteps of 32)
#define DELTA  3e-4f      // risky-gap threshold (>=100x expected logit error)
#define DELTA2 1e-3f      // candidate window around v2

typedef __bf16 bf16x8 __attribute__((ext_vector_type(8)));
typedef float f32x4 __attribute__((ext_vector_type(4)));

__device__ __forceinline__ void cvt_split(float f, ushort& h, ushort& l) {
    uint u = __float_as_uint(f);
    uint hr = (u + (0x7FFFu + ((u >> 16) & 1u))) >> 16;
    h = (ushort)hr;
    float hf = __uint_as_float(hr << 16);
    uint v = __float_as_uint(f - hf);
    l = (ushort)((v + (0x7FFFu + ((v >> 16) & 1u))) >> 16);
}

// W [64][2048] fp32 -> frag-major bf16 hi/lo (verbatim r6 layout, refcheck'd):
// o = (eg*64 + ks)*512 + lane*8 + j <-> e = eg*16+(lane&15), k = ks*32+(lane>>4)*8+j
__global__ void conv_w_kernel(const float* __restrict__ W,
                              ushort* __restrict__ whf, ushort* __restrict__ wlf) {
    const int o = blockIdx.x * 256 + threadIdx.x;   // 0..131071
    const int egks = o >> 9;
    const int lane = (o >> 3) & 63;
    const int j = o & 7;
    const int e = (egks >> 6) * 16 + (lane & 15);
    const int k = (egks & 63) * 32 + (lane >> 4) * 8 + j;
    ushort h, lo;
    cvt_split(W[e * C_IN + k], h, lo);
    whf[o] = h;
    wlf[o] = lo;
}

__device__ __forceinline__ void glds16(const void* g, void* l) {
    __builtin_amdgcn_global_load_lds(
        (const __attribute__((address_space(1))) uint32_t*)g,
        (__attribute__((address_space(3))) uint32_t*)l, 16, 0, 0);
}

__device__ __forceinline__ void cvt8(const float4 a, const float4 b2,
                                     uint4& hv, uint4& lv) {
    ushort h[8], q[8];
    cvt_split(a.x, h[0], q[0]);  cvt_split(a.y, h[1], q[1]);
    cvt_split(a.z, h[2], q[2]);  cvt_split(a.w, h[3], q[3]);
    cvt_split(b2.x, h[4], q[4]); cvt_split(b2.y, h[5], q[5]);
    cvt_split(b2.z, h[6], q[6]); cvt_split(b2.w, h[7], q[7]);
    hv = (uint4){(uint)h[0] | ((uint)h[1] << 16), (uint)h[2] | ((uint)h[3] << 16),
                 (uint)h[4] | ((uint)h[5] << 16), (uint)h[6] | ((uint)h[7] << 16)};
    lv = (uint4){(uint)q[0] | ((uint)q[1] << 16), (uint)q[2] | ((uint)q[3] << 16),
                 (uint)q[4] | ((uint)q[5] << 16), (uint)q[6] | ((uint)q[7] << 16)};
}

// issue slice SC1: per wave 8 W-gloads (1KB contiguous, eg=w) + 8 x-gloads
// (2 rows x 512B contiguous bursts, pre-swizzled source, wave-PRIVATE rows)
#define ISSUE(SC1) do {                                                       \
    char* wdst_ = smem + 65536 + ((SC1) & 1) * 32768;                         \
    _Pragma("unroll") for (int ks_ = 0; ks_ < 4; ++ks_) {                     \
        const size_t so_ = ((size_t)(w * 64 + (SC1) * 4 + ks_)) * 512 + l * 8;\
        glds16(whf + so_, wdst_ + (w * 4 + ks_) * 2048);                      \
        glds16(wlf + so_, wdst_ + (w * 4 + ks_) * 2048 + 1024);               \
    }                                                                         \
    char* xdst_ = smem + ((SC1) & 1) * 32768;                                 \
    _Pragma("unroll") for (int i_ = 0; i_ < 8; ++i_) {                        \
        const int r_ = w * 16 + 2 * i_ + (l >> 5);                            \
        const int sw_ = ((l & 31) * 16) ^ ((r_ & 15) << 5);                   \
        glds16((const char*)x + (size_t)(t0 + r_) * 8192 + (SC1) * 512 + sw_, \
               xdst_ + (w * 16 + 2 * i_) * 512);                              \
    }                                                                         \
    __builtin_amdgcn_sched_barrier(0);                                        \
} while (0)

// Main: 256 blocks x 256 thr (4 waves) = 1 block/CU, 128 KB LDS.
// Block: 64 tokens x 64 experts x full K, slice-cadence pipeline:
//   per slice: vmcnt(0) [slice data is 1 slice old ~3200cy >> 900cy HBM]
//   -> lgkmcnt(0) -> s_barrier -> issue slice sc+1 -> 4 ksteps pure-LDS
//   compute (12 MFMA + 10 ds_read + cvt per kstep). No mid-slice waits,
//   no fast/slow FIFO mixing, race-free (lgkm drain before barrier).
// x: fp32 [2][64 rows][512B] swizzled (32B units XOR row&15).
// W: bf16 hi/lo [2][4 eg][4 ks][2KB], frag-major source.
__global__ __launch_bounds__(256, 1) void topk_gate_kernel(
    const float* __restrict__ x, const float* __restrict__ Wf,
    const float* __restrict__ b, const ushort* __restrict__ whf,
    const ushort* __restrict__ wlf, float* __restrict__ out)
{
    __shared__ __align__(16) char smem[131072];

    const int tid = threadIdx.x;
    const int w = tid >> 6, l = tid & 63;
    const int tr = l & 15, kq = l >> 4;
    const int t0 = blockIdx.x * TPB;

    f32x4 acc[4];
#pragma unroll
    for (int eg = 0; eg < 4; ++eg) acc[eg] = (f32x4){0.f, 0.f, 0.f, 0.f};

    ISSUE(0);

#pragma unroll 1
    for (int sc = 0; sc < NSLICE; ++sc) {
        asm volatile("s_waitcnt vmcnt(0)" ::: "memory");
        __builtin_amdgcn_sched_barrier(0);
        asm volatile("s_waitcnt lgkmcnt(0)" ::: "memory");
        __builtin_amdgcn_sched_barrier(0);
        __builtin_amdgcn_s_barrier();
        if (sc + 1 < NSLICE) ISSUE(sc + 1);

        const char* xb = smem + (sc & 1) * 32768 + (w * 16) * 512;
        const char* wb = smem + 65536 + (sc & 1) * 32768;
#pragma unroll
        for (int J = 0; J < 4; ++J) {
            const int ao = tr * 512 + ((J * 128 + kq * 32) ^ (tr << 5));
            float4 a0 = *(const float4*)(xb + ao);
            float4 a1 = *(const float4*)(xb + ao + 16);
            uint4 hv, lv;
            cvt8(a0, a1, hv, lv);
            bf16x8 ah = __builtin_bit_cast(bf16x8, hv);
            bf16x8 al = __builtin_bit_cast(bf16x8, lv);
            __builtin_amdgcn_s_setprio(1);
#pragma unroll
            for (int eg = 0; eg < 4; ++eg) {
                uint4 bhu = *(const uint4*)(wb + (eg * 4 + J) * 2048 + l * 16);
                uint4 blu = *(const uint4*)(wb + (eg * 4 + J) * 2048 + 1024 + l * 16);
                bf16x8 bh = __builtin_bit_cast(bf16x8, bhu);
                bf16x8 bl = __builtin_bit_cast(bf16x8, blu);
                acc[eg] = __builtin_amdgcn_mfma_f32_16x16x32_bf16(ah, bh, acc[eg], 0, 0, 0);
                acc[eg] = __builtin_amdgcn_mfma_f32_16x16x32_bf16(al, bh, acc[eg], 0, 0, 0);
                acc[eg] = __builtin_amdgcn_mfma_f32_16x16x32_bf16(ah, bl, acc[eg], 0, 0, 0);
            }
            __builtin_amdgcn_s_setprio(0);
        }
    }

    // ---- partials: [64][65] fp32 overlays x buf0 (final slice read buf1) ----
    float* part = (float*)smem;
#pragma unroll
    for (int eg = 0; eg < 4; ++eg)
#pragma unroll
    for (int r = 0; r < 4; ++r)
        part[(w * 16 + kq * 4 + r) * 65 + eg * 16 + tr] = acc[eg][r];
    __syncthreads();

    // ---- softmax + top-2 + exact-fp32 repair (wave w: tokens w*16..+15) ----
    const int e = l;
    const float be = b[e];
    for (int ti = 0; ti < 16; ++ti) {
        const int t = w * 16 + ti;
        float logit = part[t * 65 + e] + be;

        float v1, v2, v3; int i1, i2;
        for (int pass = 0; pass < 2; ++pass) {
            v1 = logit; i1 = e;
#pragma unroll
            for (int off = 32; off >= 1; off >>= 1) {
                float ov = __shfl_xor(v1, off, 64);
                int   oi = __shfl_xor(i1, off, 64);
                if (ov > v1 || (ov == v1 && oi < i1)) { v1 = ov; i1 = oi; }
            }
            v2 = (e == i1) ? -3.4e38f : logit;
            i2 = (e == i1) ? N_EXP : e;
#pragma unroll
            for (int off = 32; off >= 1; off >>= 1) {
                float ov = __shfl_xor(v2, off, 64);
                int   oi = __shfl_xor(i2, off, 64);
                if (ov > v2 || (ov == v2 && oi < i2)) { v2 = ov; i2 = oi; }
            }
            v3 = (e == i1 || e == i2) ? -3.4e38f : logit;
#pragma unroll
            for (int off = 32; off >= 1; off >>= 1) {
                float ov = __shfl_xor(v3, off, 64);
                v3 = (ov > v3) ? ov : v3;
            }
            if (pass == 1) break;
            const bool risky = (v1 - v2 < DELTA) || (v2 - v3 < DELTA);
            if (!risky) break;
            // exact fp32 recompute of candidate experts (wave-uniform path)
            unsigned long long cm = __ballot(logit >= v2 - DELTA2);
            const float* xr = x + (size_t)(t0 + t) * C_IN;
            while (cm) {
                const int ce = __ffsll((unsigned long long)cm) - 1;
                cm &= cm - 1;
                const float* wr = Wf + (size_t)ce * C_IN;
                float p = 0.f;
#pragma unroll 8
                for (int i = 0; i < 32; ++i)
                    p = fmaf(xr[l + 64 * i], wr[l + 64 * i], p);
#pragma unroll
                for (int off = 32; off >= 1; off >>= 1)
                    p += __shfl_xor(p, off, 64);
                if (e == ce) logit = p + be;
            }
        }

        float ex = expf(logit - v1);
        float ssum = ex;
#pragma unroll
        for (int off = 32; off >= 1; off >>= 1)
            ssum += __shfl_xor(ssum, off, 64);
        const float inv = 1.0f / ssum;
        const float p1 = inv;
        const float p2 = expf(v2 - v1) * inv;
        const float o = (e == i1) ? p1 : ((e == i2) ? p2 : 0.0f);
        out[(size_t)(t0 + t) * N_EXP + e] = o;
    }
}

extern "C" void kernel_launch(void* const* d_in, const int* in_sizes, int n_in,
                              void* d_out, int out_size, void* d_ws, size_t ws_size,
                              hipStream_t stream) {
    const float* x = (const float*)d_in[0];   // [4,4096,2048]
    const float* W = (const float*)d_in[1];   // [64,2048]
    const float* b = (const float*)d_in[2];   // [64]
    float* out = (float*)d_out;               // [4,4096,64]

    ushort* whf = (ushort*)d_ws;              // frag-major bf16 hi, 256 KB
    ushort* wlf = whf + N_EXP * C_IN;         // frag-major bf16 lo, 256 KB

    conv_w_kernel<<<512, 256, 0, stream>>>(W, whf, wlf);

    const int tokens = in_sizes[0] / C_IN;    // 16384
    const int grid = tokens / TPB;            // 256
    topk_gate_kernel<<<grid, 256, 0, stream>>>(x, W, b, whf, wlf, out);
}